// Round 11
// baseline (88.295 us; speedup 1.0000x reference)
//
#include <hip/hip_runtime.h>
#include <hip/hip_bf16.h>
#include <cstdint>
#include <cstddef>

#define B_ROWS 8192
#define KDIM   4096
#define IN_DIM 2048
#define HIDDEN 2048
#define NJ     32           // 4 gates x 8 wires
#define BK     64           // k-subtile per pipeline stage
#define SUBT   (KDIM / BK)  // 64 subtiles (full K per block)
#define MROWS  32           // rows per block (2 waves x 16)
#define TPB1   128          // 2 waves
#define NBUF   4            // pipeline buffers (depth-2 prefetch, race-free)
#define GRID1  (B_ROWS / MROWS) // 256 blocks = 1 per CU

typedef __bf16 bf16x8 __attribute__((ext_vector_type(8)));
typedef float  f32x4  __attribute__((ext_vector_type(4)));

__device__ __forceinline__ bf16x8 cvt8(f32x4 a, f32x4 b) {
    bf16x8 r;
    r[0] = (__bf16)a.x; r[1] = (__bf16)a.y; r[2] = (__bf16)a.z; r[3] = (__bf16)a.w;
    r[4] = (__bf16)b.x; r[5] = (__bf16)b.y; r[6] = (__bf16)b.z; r[7] = (__bf16)b.w;
    return r;
}

// async global->LDS, 16 B per lane; LDS dest = wave-uniform base + lane*16
__device__ __forceinline__ void gload_lds16(const void* g, void* lds) {
    __builtin_amdgcn_global_load_lds(
        (const __attribute__((address_space(1))) void*)g,
        (__attribute__((address_space(3))) void*)lds, 16, 0, 0);
}

// ===== Pass 1: full-K MFMA GEMM + cos + block reduce -> qpart[256][4] =====
// grid = 256 blocks (1/CU) * 128 thr (2 waves); block = 32 rows x K=4096.
// LDS: A fp32 [NBUF][32][64] (8 KB/buf), W fp32 [NBUF][32][64] (8 KB/buf).
// XOR swizzle both sides (rule #21): 16B-unit u ^= (row & 7).
// No Spart, no atomics: epilogue reduces cos() in-block, writes 4 floats.
extern "C" __global__ __launch_bounds__(TPB1)
void p1_full(const float* __restrict__ x,  const float* __restrict__ hx,
             const float* __restrict__ Wf, const float* __restrict__ Wi,
             const float* __restrict__ Wg, const float* __restrict__ Wo,
             const float* __restrict__ bfp, const float* __restrict__ bip,
             const float* __restrict__ bgp, const float* __restrict__ bop,
             float* __restrict__ qpart)
{
    __shared__ float Abuf[NBUF][MROWS * BK];   // 4 x 8 KB
    __shared__ float Bbuf[NBUF][NJ * BK];      // 4 x 8 KB
    __shared__ float qsh[2][4];

    const int tid  = threadIdx.x;
    const int wave = tid >> 6;                  // 0..1
    const int lane = tid & 63;
    const int lrow = lane & 15;
    const int rowblk = blockIdx.x * MROWS;

    // ---- A sources: k<2048 from x, k>=2048 from hx (row stride 2048 both)
    const float* Ax = x  + (size_t)rowblk * IN_DIM;
    const float* Ah = hx + (size_t)rowblk * HIDDEN;

    // ---- A staging addresses (pre-swizzled global source) ----
    // instr (wave,p): rows (wave*4+p)*4 + (l>>4), unit l&15; src unit ^= row&7
    int aOff[4];
#pragma unroll
    for (int p = 0; p < 4; ++p) {
        const int r  = (wave * 4 + p) * 4 + (lane >> 4);
        const int cs = (lane & 15) ^ (r & 7);
        aOff[p] = r * 2048 + cs * 4;            // float offset
    }
    // ---- W staging: slab sl = wave*4+i covers j rows sl*4..sl*4+3; all 4
    // rows of a slab live in ONE gate matrix (gate = sl>>1 = wave*2 + (i>>1)).
    const float* Ws0 = wave ? Wg : Wf;          // slabs i=0,1
    const float* Ws1 = wave ? Wo : Wi;          // slabs i=2,3
    int bOffp[4];
#pragma unroll
    for (int i = 0; i < 4; ++i) {
        const int j  = (wave * 4 + i) * 4 + (lane >> 4);  // 0..31
        const int j7 = j & 7;                   // row within gate matrix
        bOffp[i] = j7 * KDIM + (((lane & 15) ^ j7) * 4);  // float offset
    }

    // ---- swizzled ds_read_b128 byte offsets ----
    const int row_r = wave * 16 + lrow;         // A row; row_r&7 == lane&7
    int offA0[2], offA1[2], offB00[2], offB01[2], offB10[2], offB11[2];
#pragma unroll
    for (int st = 0; st < 2; ++st) {
        const int cu = st * 8 + (lane >> 4) * 2;
        offA0[st]  = row_r * 256 + (((cu + 0) ^ (lane & 7)) * 16);
        offA1[st]  = row_r * 256 + (((cu + 1) ^ (lane & 7)) * 16);
        offB00[st] = lrow * 256        + (((cu + 0) ^ (lane & 7)) * 16);
        offB01[st] = lrow * 256        + (((cu + 1) ^ (lane & 7)) * 16);
        offB10[st] = (lrow + 16) * 256 + (((cu + 0) ^ (lane & 7)) * 16);
        offB11[st] = (lrow + 16) * 256 + (((cu + 1) ^ (lane & 7)) * 16);
    }

    f32x4 acc0 = {0.f, 0.f, 0.f, 0.f};   // j = lrow      (gates f,i)
    f32x4 acc1 = {0.f, 0.f, 0.f, 0.f};   // j = 16 + lrow (gates g,o)

    auto issue = [&](int s) {
        const int b = s & (NBUF - 1);
        const float* As = (s < SUBT / 2) ? (Ax + s * BK) : (Ah + (s - SUBT / 2) * BK);
#pragma unroll
        for (int p = 0; p < 4; ++p)
            gload_lds16(As + aOff[p], (char*)&Abuf[b][0] + (wave * 4 + p) * 1024);
#pragma unroll
        for (int i = 0; i < 4; ++i) {
            const float* Wsrc = (i < 2) ? Ws0 : Ws1;
            gload_lds16(Wsrc + bOffp[i] + s * BK,
                        (char*)&Bbuf[b][0] + (wave * 4 + i) * 1024);
        }
    };
    auto compute = [&](int s) {
        const int b = s & (NBUF - 1);
        const char* Ab = (const char*)&Abuf[b][0];
        const char* Bb = (const char*)&Bbuf[b][0];
#pragma unroll
        for (int st = 0; st < 2; ++st) {
            f32x4 a0  = *reinterpret_cast<const f32x4*>(Ab + offA0[st]);
            f32x4 a1  = *reinterpret_cast<const f32x4*>(Ab + offA1[st]);
            f32x4 w00 = *reinterpret_cast<const f32x4*>(Bb + offB00[st]);
            f32x4 w01 = *reinterpret_cast<const f32x4*>(Bb + offB01[st]);
            f32x4 w10 = *reinterpret_cast<const f32x4*>(Bb + offB10[st]);
            f32x4 w11 = *reinterpret_cast<const f32x4*>(Bb + offB11[st]);
            bf16x8 af  = cvt8(a0, a1);
            bf16x8 bf0 = cvt8(w00, w01);
            bf16x8 bf1 = cvt8(w10, w11);
            acc0 = __builtin_amdgcn_mfma_f32_16x16x32_bf16(af, bf0, acc0, 0, 0, 0);
            acc1 = __builtin_amdgcn_mfma_f32_16x16x32_bf16(af, bf1, acc1, 0, 0, 0);
        }
    };

    // ---- pipeline: depth-2 prefetch, counted vmcnt, raw barriers ----
    // 8 loads/wave/batch; after issue(s+2) outstanding = {s+1,s+2} = 16
    // -> vmcnt(16) implies batch s landed. Tail: vmcnt(8), then vmcnt(0).
    issue(0);
    issue(1);
#pragma unroll 4
    for (int s = 0; s < SUBT - 2; ++s) {
        issue(s + 2);
        asm volatile("s_waitcnt vmcnt(16)" ::: "memory");
        __builtin_amdgcn_s_barrier();           // batch-s writes visible
        __builtin_amdgcn_sched_barrier(0);      // no ds_read hoist (rule #18)
        compute(s);
        // reuse safety: iter-s writes target buf (s+2)%4; slowest concurrent
        // reader is compute(s-1) on buf (s-1)%4 -- distance 3 mod 4 != 0.
    }
    asm volatile("s_waitcnt vmcnt(8)" ::: "memory");
    __builtin_amdgcn_s_barrier();
    __builtin_amdgcn_sched_barrier(0);
    compute(SUBT - 2);
    asm volatile("s_waitcnt vmcnt(0)" ::: "memory");
    __builtin_amdgcn_s_barrier();
    __builtin_amdgcn_sched_barrier(0);
    compute(SUBT - 1);

    // ---- epilogue: bias + cos + reduce (no Spart, no atomics) ----
    // acc0[r] = dot(row m0+r, j=lrow); acc1[r] = dot(row m0+r, j=16+lrow)
    const float b0v = ((lrow & 8) ? bip : bfp)[lrow & 7];   // gate f/i
    const float b1v = ((lrow & 8) ? bop : bgp)[lrow & 7];   // gate g/o
    float v0 = 0.f, v1 = 0.f;
#pragma unroll
    for (int r = 0; r < 4; ++r) {
        v0 += cosf(acc0[r] + b0v);
        v1 += cosf(acc1[r] + b1v);
    }
    // reduce over lanes sharing lane-bit3 (gate split): XOR bits {0,1,2,4,5}
#pragma unroll
    for (int m = 0; m < 5; ++m) {
        const int msk = (int[]){1, 2, 4, 16, 32}[m];
        v0 += __shfl_xor(v0, msk, 64);
        v1 += __shfl_xor(v1, msk, 64);
    }
    if ((lane & 55) == 0) {                     // lanes 0 and 8
        const int gg = (lane >> 3) & 1;
        qsh[wave][gg]     = v0;                 // gates 0/1
        qsh[wave][gg + 2] = v1;                 // gates 2/3
    }
    __syncthreads();
    if (tid < 4) qpart[blockIdx.x * 4 + tid] = qsh[0][tid] + qsh[1][tid];
}

// ===== Pass 2: reduce qpart + elementwise LSTM update =====
extern "C" __global__ __launch_bounds__(256)
void p3_elementwise(const float* __restrict__ cx, const float* __restrict__ qpart,
                    float* __restrict__ out)
{
    __shared__ float qs[4][4];                  // [wave][gate]
    const int tid  = threadIdx.x;
    const int wave = tid >> 6;
    const int lane = tid & 63;

    // block-local reduce of qpart[256][4] (4 KB, L2-resident)
    f32x4 qp = *reinterpret_cast<const f32x4*>(qpart + tid * 4);
#pragma unroll
    for (int m = 1; m <= 32; m <<= 1) {
        qp.x += __shfl_xor(qp.x, m, 64);
        qp.y += __shfl_xor(qp.y, m, 64);
        qp.z += __shfl_xor(qp.z, m, 64);
        qp.w += __shfl_xor(qp.w, m, 64);
    }
    if (lane == 0) {
        qs[wave][0] = qp.x; qs[wave][1] = qp.y;
        qs[wave][2] = qp.z; qs[wave][3] = qp.w;
    }
    __syncthreads();
    const float qf = qs[0][0] + qs[1][0] + qs[2][0] + qs[3][0];
    const float qi = qs[0][1] + qs[1][1] + qs[2][1] + qs[3][1];
    const float qg = qs[0][2] + qs[1][2] + qs[2][2] + qs[3][2];
    const float qo = qs[0][3] + qs[1][3] + qs[2][3] + qs[3][3];

    const float f  = 1.f / (1.f + expf(-qf));
    const float ii = 1.f / (1.f + expf(-qi));
    const float g  = tanhf(qg);
    const float o  = 1.f / (1.f + expf(-qo));
    const float ig = ii * g;

    const size_t N  = (size_t)B_ROWS * HIDDEN;
    const size_t N4 = N >> 2;
    const f32x4* cx4 = (const f32x4*)cx;
    f32x4* outh = (f32x4*)out;
    f32x4* outc = (f32x4*)(out + N);

    for (size_t idx = (size_t)blockIdx.x * blockDim.x + tid; idx < N4;
         idx += (size_t)gridDim.x * blockDim.x) {
        f32x4 c = __builtin_nontemporal_load(cx4 + idx);  // streaming, no reuse
        f32x4 cn, hn;
        cn.x = fmaf(f, c.x, ig);
        cn.y = fmaf(f, c.y, ig);
        cn.z = fmaf(f, c.z, ig);
        cn.w = fmaf(f, c.w, ig);
        hn.x = o * tanhf(cn.x);
        hn.y = o * tanhf(cn.y);
        hn.z = o * tanhf(cn.z);
        hn.w = o * tanhf(cn.w);
        outc[idx] = cn;
        outh[idx] = hn;
    }
}

// ---------------- launcher: TWO dispatches, no memset, no atomics ---------
extern "C" void kernel_launch(void* const* d_in, const int* in_sizes, int n_in,
                              void* d_out, int out_size, void* d_ws, size_t ws_size,
                              hipStream_t stream)
{
    const float* x  = (const float*)d_in[0];
    const float* hx = (const float*)d_in[1];
    const float* cx = (const float*)d_in[2];
    const float* Wf = (const float*)d_in[3];
    const float* bf = (const float*)d_in[4];
    const float* Wi = (const float*)d_in[5];
    const float* bi = (const float*)d_in[6];
    const float* Wg = (const float*)d_in[7];
    const float* bg = (const float*)d_in[8];
    const float* Wo = (const float*)d_in[9];
    const float* bo = (const float*)d_in[10];
    float* out = (float*)d_out;

    float* qpart = (float*)d_ws;   // [256][4] f32, fully overwritten each call

    p1_full<<<dim3(GRID1), dim3(TPB1), 0, stream>>>(
        x, hx, Wf, Wi, Wg, Wo, bf, bi, bg, bo, qpart);
    p3_elementwise<<<dim3(2048), dim3(256), 0, stream>>>(cx, qpart, out);
}

// Round 12
// 70.502 us; speedup vs baseline: 1.2524x; 1.2524x over previous
//
#include <hip/hip_runtime.h>
#include <hip/hip_bf16.h>
#include <cstdint>
#include <cstddef>

#define B_ROWS 8192
#define KDIM   4096
#define IN_DIM 2048
#define HIDDEN 2048
#define NJ     32           // 4 gates x 8 wires
#define KC     8            // K-split across blocks
#define CHUNK  (KDIM / KC)  // 512
#define BK     64           // k-subtile per pipeline stage
#define SUBT   (CHUNK / BK) // 8
#define MROWS  64           // rows per block (4 waves x 16)
#define NBUF   4            // pipeline buffers (depth-2 prefetch, race-free)

typedef __bf16 bf16x8 __attribute__((ext_vector_type(8)));
typedef __bf16 bf16x4 __attribute__((ext_vector_type(4)));
typedef float  f32x4  __attribute__((ext_vector_type(4)));

__device__ __forceinline__ bf16x8 cvt8(f32x4 a, f32x4 b) {
    bf16x8 r;
    r[0] = (__bf16)a.x; r[1] = (__bf16)a.y; r[2] = (__bf16)a.z; r[3] = (__bf16)a.w;
    r[4] = (__bf16)b.x; r[5] = (__bf16)b.y; r[6] = (__bf16)b.z; r[7] = (__bf16)b.w;
    return r;
}

// async global->LDS, 16 B per lane; LDS dest = wave-uniform base + lane*16
__device__ __forceinline__ void gload_lds16(const void* g, void* lds) {
    __builtin_amdgcn_global_load_lds(
        (const __attribute__((address_space(1))) void*)g,
        (__attribute__((address_space(3))) void*)lds, 16, 0, 0);
}

// ---------------- Pass 0: pack weights to bf16 [32][4096]; zero q ---------
extern "C" __global__ __launch_bounds__(256)
void w_pack(const float* __restrict__ Wf, const float* __restrict__ Wi,
            const float* __restrict__ Wg, const float* __restrict__ Wo,
            __bf16* __restrict__ Wb, float* __restrict__ q)
{
    if (blockIdx.x == 0 && threadIdx.x < 4) q[threadIdx.x] = 0.f;

    const int t    = blockIdx.x * 256 + threadIdx.x;   // 0 .. 32767
    const int idx4 = t << 2;
    const int j    = idx4 >> 12;
    const int k    = idx4 & (KDIM - 1);
    const float* W = (j < 8) ? Wf : (j < 16) ? Wi : (j < 24) ? Wg : Wo;
    f32x4 v = *reinterpret_cast<const f32x4*>(W + (size_t)(j & 7) * KDIM + k);
    bf16x4 b;
    b[0] = (__bf16)v.x; b[1] = (__bf16)v.y; b[2] = (__bf16)v.z; b[3] = (__bf16)v.w;
    *reinterpret_cast<bf16x4*>(Wb + idx4) = b;
}

// ------- Pass 1: split-K MFMA GEMM, global_load_lds + counted-vmcnt -------
// grid = 128 mblocks * 8 kc; block = 256 thr (4 waves) = 64 rows x 512 k.
// LDS: A fp32 [NBUF][64][64] (16 KB/buf), B bf16 [NBUF][32][64] (4 KB/buf).
// XOR swizzle (both sides): 16B-unit index cu ^= (row & 7).
// Spart layout: [KC][B_ROWS][NJ]
extern "C" __global__ __launch_bounds__(256)
void p1_mfma(const float* __restrict__ x, const float* __restrict__ hx,
             const __bf16* __restrict__ Wb, float* __restrict__ Spart)
{
    __shared__ float  Abuf[NBUF][MROWS * BK];   // 4 x 16 KB
    __shared__ __bf16 Bbuf[NBUF][NJ * BK];      // 4 x 4 KB

    const int bid  = blockIdx.x;
    const int kc   = bid & (KC - 1);
    const int mb   = bid >> 3;                  // 0..127
    const int tid  = threadIdx.x;
    const int wave = tid >> 6;
    const int lane = tid & 63;
    const int rowblk = mb * MROWS;
    const int k0   = kc * CHUNK;

    // ---- global sources (x / hx share row stride 2048; chunk never straddles)
    const float* Aglob = (kc < 4)
        ? (x  + (size_t)rowblk * IN_DIM + k0)
        : (hx + (size_t)rowblk * HIDDEN + (k0 - IN_DIM));
    const __bf16* Bglob = Wb + k0;

    // ---- staging addresses (pre-swizzled global source, rule #21) ----
    // A instr (wave,p): LDS rows R..R+3 linear; lane l -> row R+(l>>4), cu l&15.
    // Source element = (row, (l&15) ^ (row&7)); wave*16 === 0 (mod 8).
    int aOff[4];
#pragma unroll
    for (int p = 0; p < 4; ++p) {
        const int r  = wave * 16 + p * 4 + (lane >> 4);
        const int cs = (lane & 15) ^ ((p * 4 + (lane >> 4)) & 7);
        aOff[p] = r * 2048 + cs * 4;            // float offset
    }
    // B instr (one per wave): j = wave*8 + (l>>3), cu = l&7, src cu ^= (j&7)
    const int bj   = wave * 8 + (lane >> 3);
    const int bOff = bj * KDIM + (((lane & 7) ^ ((lane >> 3) & 7)) * 8); // bf16 off

    // ---- read addresses (swizzled ds_read_b128), precomputed bytes ----
    const int lrow  = lane & 15;
    const int row_r = wave * 16 + lrow;          // A row (wave-private)
    int offA0[2], offA1[2], offB0[2], offB1[2];
#pragma unroll
    for (int st = 0; st < 2; ++st) {
        const int cu = st * 8 + (lane >> 4) * 2;            // A 16B-unit
        offA0[st] = row_r * 256 + ((cu + 0) ^ (lane & 7)) * 16;
        offA1[st] = row_r * 256 + ((cu + 1) ^ (lane & 7)) * 16;
        const int cb = st * 4 + (lane >> 4);                // B 16B-unit
        offB0[st] = lrow * 128        + (cb ^ (lrow & 7)) * 16;
        offB1[st] = (lrow + 16) * 128 + (cb ^ (lrow & 7)) * 16;
    }

    f32x4 acc0 = {0.f, 0.f, 0.f, 0.f};
    f32x4 acc1 = {0.f, 0.f, 0.f, 0.f};

    auto issue = [&](int s) {
        const int b = s & (NBUF - 1);
#pragma unroll
        for (int p = 0; p < 4; ++p)
            gload_lds16(Aglob + aOff[p] + s * BK, &Abuf[b][(wave * 4 + p) * 256]);
        gload_lds16(Bglob + bOff + s * BK, &Bbuf[b][wave * 512]);
    };
    auto compute = [&](int s) {
        const int b = s & (NBUF - 1);
        const char* Ab = (const char*)&Abuf[b][0];
        const char* Bb = (const char*)&Bbuf[b][0];
#pragma unroll
        for (int st = 0; st < 2; ++st) {
            f32x4 a0 = *reinterpret_cast<const f32x4*>(Ab + offA0[st]);
            f32x4 a1 = *reinterpret_cast<const f32x4*>(Ab + offA1[st]);
            bf16x8 af = cvt8(a0, a1);
            bf16x8 b0 = *reinterpret_cast<const bf16x8*>(Bb + offB0[st]);
            bf16x8 b1 = *reinterpret_cast<const bf16x8*>(Bb + offB1[st]);
            acc0 = __builtin_amdgcn_mfma_f32_16x16x32_bf16(af, b0, acc0, 0, 0, 0);
            acc1 = __builtin_amdgcn_mfma_f32_16x16x32_bf16(af, b1, acc1, 0, 0, 0);
        }
    };

    // ---- pipeline: depth-2 prefetch, counted vmcnt, raw barriers ----
    // vmcnt math: 5 loads/batch; after issue(s+2), outstanding = {s+1,s+2}=10
    // -> vmcnt(10) implies batch s landed. Tail: s=6 -> 5, s=7 -> 0.
    issue(0);
    issue(1);
#pragma unroll
    for (int s = 0; s < SUBT; ++s) {
        if (s + 2 < SUBT) issue(s + 2);
        if (s < SUBT - 2)
            asm volatile("s_waitcnt vmcnt(10)" ::: "memory");
        else if (s == SUBT - 2)
            asm volatile("s_waitcnt vmcnt(5)" ::: "memory");
        else
            asm volatile("s_waitcnt vmcnt(0)" ::: "memory");
        __builtin_amdgcn_s_barrier();           // batch-s writes visible
        __builtin_amdgcn_sched_barrier(0);      // no ds_read hoist (rule #18)
        compute(s);
        // reuse safety: iter-s writes target buf (s+2)%4; slowest concurrent
        // reader is compute(s-1) on buf (s-1)%4 -- distance 3 mod 4 != 0.
    }

    // D layout (16x16x32): col = lane&15, row = (lane>>4)*4 + reg
    const int row0 = rowblk + wave * 16;
    float* sp = Spart + ((size_t)kc * B_ROWS + row0) * NJ;
    const int m0 = (lane >> 4) * 4;
#pragma unroll
    for (int r = 0; r < 4; ++r) {
        sp[(size_t)(m0 + r) * NJ + lrow]      = acc0[r];
        sp[(size_t)(m0 + r) * NJ + 16 + lrow] = acc1[r];
    }
}

// ---------------- Pass 2: sum partials, bias, cos, reduce to q[4] ----------
// grid = 256 blocks * 256 thr = 65536 threads; each thread: 4 (row,j) pairs
extern "C" __global__ __launch_bounds__(256)
void p2_cos_reduce(const float* __restrict__ Spart,
                   const float* __restrict__ bf, const float* __restrict__ bi,
                   const float* __restrict__ bg, const float* __restrict__ bo,
                   float* __restrict__ q)
{
    __shared__ float ql[4];
    if (threadIdx.x < 4) ql[threadIdx.x] = 0.f;
    __syncthreads();

    const int t    = blockIdx.x * 256 + threadIdx.x;  // 0..65535
    const int j    = t & 31;
    const int gate = j >> 3;
    const float* Bp = (gate == 0) ? bf : (gate == 1) ? bi : (gate == 2) ? bg : bo;
    const float bj = Bp[j & 7];

    float accg = 0.f;
#pragma unroll
    for (int i = 0; i < 4; ++i) {
        const int row = (t >> 5) + i * 2048;
        float s = 0.f;
#pragma unroll
        for (int kc = 0; kc < KC; ++kc)
            s += Spart[((size_t)kc * B_ROWS + row) * NJ + j];
        accg += cosf(s + bj);
    }

    accg += __shfl_xor(accg, 1, 64);
    accg += __shfl_xor(accg, 2, 64);
    accg += __shfl_xor(accg, 4, 64);
    if ((threadIdx.x & 7) == 0) atomicAdd(&ql[gate], accg);
    __syncthreads();
    if (threadIdx.x < 4) atomicAdd(&q[threadIdx.x], ql[threadIdx.x]);
}

// ---------------- Pass 3: elementwise LSTM update ----------------
// cx: NORMAL load (re-read every replay -> keep L3-resident).
// out: NON-TEMPORAL store (write-once stream -> don't evict inputs from L3).
extern "C" __global__ __launch_bounds__(256)
void p3_elementwise(const float* __restrict__ cx, const float* __restrict__ q,
                    float* __restrict__ out)
{
    const float qf = q[0], qi = q[1], qg = q[2], qo = q[3];
    const float f  = 1.f / (1.f + expf(-qf));
    const float ii = 1.f / (1.f + expf(-qi));
    const float g  = tanhf(qg);
    const float o  = 1.f / (1.f + expf(-qo));
    const float ig = ii * g;

    const size_t N  = (size_t)B_ROWS * HIDDEN;
    const size_t N4 = N >> 2;
    const f32x4* cx4 = (const f32x4*)cx;
    f32x4* outh = (f32x4*)out;
    f32x4* outc = (f32x4*)(out + N);

    for (size_t idx = (size_t)blockIdx.x * blockDim.x + threadIdx.x; idx < N4;
         idx += (size_t)gridDim.x * blockDim.x) {
        f32x4 c = cx4[idx];                       // L3-resident across replays
        f32x4 cn, hn;
        cn.x = fmaf(f, c.x, ig);
        cn.y = fmaf(f, c.y, ig);
        cn.z = fmaf(f, c.z, ig);
        cn.w = fmaf(f, c.w, ig);
        hn.x = o * tanhf(cn.x);
        hn.y = o * tanhf(cn.y);
        hn.z = o * tanhf(cn.z);
        hn.w = o * tanhf(cn.w);
        __builtin_nontemporal_store(cn, outc + idx);
        __builtin_nontemporal_store(hn, outh + idx);
    }
}

// ---------------- launcher ----------------
extern "C" void kernel_launch(void* const* d_in, const int* in_sizes, int n_in,
                              void* d_out, int out_size, void* d_ws, size_t ws_size,
                              hipStream_t stream)
{
    const float* x  = (const float*)d_in[0];
    const float* hx = (const float*)d_in[1];
    const float* cx = (const float*)d_in[2];
    const float* Wf = (const float*)d_in[3];
    const float* bf = (const float*)d_in[4];
    const float* Wi = (const float*)d_in[5];
    const float* bi = (const float*)d_in[6];
    const float* Wg = (const float*)d_in[7];
    const float* bg = (const float*)d_in[8];
    const float* Wo = (const float*)d_in[9];
    const float* bo = (const float*)d_in[10];
    float* out = (float*)d_out;

    // ws layout: Spart [KC][8192][32] f32 (8 MB) | Wb [32][4096] bf16 | q[4]
    float*   Spart = (float*)d_ws;
    __bf16*  Wb    = (__bf16*)(Spart + (size_t)KC * B_ROWS * NJ);
    float*   q     = (float*)(Wb + (size_t)NJ * KDIM);

    w_pack<<<dim3(128), dim3(256), 0, stream>>>(Wf, Wi, Wg, Wo, Wb, q);
    p1_mfma<<<dim3(128 * KC), dim3(256), 0, stream>>>(x, hx, Wb, Spart);
    p2_cos_reduce<<<dim3(256), dim3(256), 0, stream>>>(Spart, bf, bi, bg, bo, q);
    p3_elementwise<<<dim3(2048), dim3(256), 0, stream>>>(cx, q, out);
}

// Round 13
// 69.817 us; speedup vs baseline: 1.2647x; 1.0098x over previous
//
#include <hip/hip_runtime.h>
#include <hip/hip_bf16.h>
#include <cstdint>
#include <cstddef>

#define B_ROWS 8192
#define KDIM   4096
#define IN_DIM 2048
#define HIDDEN 2048
#define NJ     32           // 4 gates x 8 wires
#define KC     4            // K-split across blocks
#define CHUNK  (KDIM / KC)  // 1024
#define BK     64           // k-subtile per pipeline stage
#define SUBT   (CHUNK / BK) // 16
#define MROWS  16           // rows per block (ONE wave)
#define TPB1   64           // 1 wave -> no s_barrier anywhere in the K-loop
#define NBUF   4            // depth-3 prefetch (single-wave: provably safe)

typedef __bf16 bf16x8 __attribute__((ext_vector_type(8)));
typedef __bf16 bf16x4 __attribute__((ext_vector_type(4)));
typedef float  f32x4  __attribute__((ext_vector_type(4)));

__device__ __forceinline__ bf16x8 cvt8(f32x4 a, f32x4 b) {
    bf16x8 r;
    r[0] = (__bf16)a.x; r[1] = (__bf16)a.y; r[2] = (__bf16)a.z; r[3] = (__bf16)a.w;
    r[4] = (__bf16)b.x; r[5] = (__bf16)b.y; r[6] = (__bf16)b.z; r[7] = (__bf16)b.w;
    return r;
}

// async global->LDS, 16 B per lane; LDS dest = wave-uniform base + lane*16
__device__ __forceinline__ void gload_lds16(const void* g, void* lds) {
    __builtin_amdgcn_global_load_lds(
        (const __attribute__((address_space(1))) void*)g,
        (__attribute__((address_space(3))) void*)lds, 16, 0, 0);
}

// ---------------- Pass 0: pack weights to bf16 [32][4096]; zero q ---------
extern "C" __global__ __launch_bounds__(256)
void w_pack(const float* __restrict__ Wf, const float* __restrict__ Wi,
            const float* __restrict__ Wg, const float* __restrict__ Wo,
            __bf16* __restrict__ Wb, float* __restrict__ q)
{
    if (blockIdx.x == 0 && threadIdx.x < 4) q[threadIdx.x] = 0.f;

    const int t    = blockIdx.x * 256 + threadIdx.x;   // 0 .. 32767
    const int idx4 = t << 2;
    const int j    = idx4 >> 12;
    const int k    = idx4 & (KDIM - 1);
    const float* W = (j < 8) ? Wf : (j < 16) ? Wi : (j < 24) ? Wg : Wo;
    f32x4 v = *reinterpret_cast<const f32x4*>(W + (size_t)(j & 7) * KDIM + k);
    bf16x4 b;
    b[0] = (__bf16)v.x; b[1] = (__bf16)v.y; b[2] = (__bf16)v.z; b[3] = (__bf16)v.w;
    *reinterpret_cast<bf16x4*>(Wb + idx4) = b;
}

// ---- Pass 1: split-K MFMA GEMM, BARRIER-FREE per-wave DMA pipelines ------
// grid = 512 mblocks * 4 kc = 2048 blocks of 64 thr (1 wave).
// LDS: A fp32 [NBUF][16][64] (4 KB/buf) + B bf16 [NBUF][32][64] (4 KB/buf)
// = 32 KB/block -> 5 blocks/CU, each an independent depth-3 pipeline.
// XOR swizzle both sides (rule #21): 16B-unit u ^= (row & 7).
// Spart layout: [KC][B_ROWS][NJ]
extern "C" __global__ __launch_bounds__(TPB1)
void p1_mfma(const float* __restrict__ x, const float* __restrict__ hx,
             const __bf16* __restrict__ Wb, float* __restrict__ Spart)
{
    __shared__ float  Abuf[NBUF][MROWS * BK];   // 4 x 4 KB
    __shared__ __bf16 Bbuf[NBUF][NJ * BK];      // 4 x 4 KB

    const int bid  = blockIdx.x;
    const int kc   = bid & (KC - 1);
    const int mb   = bid >> 2;                  // 0..511
    const int lane = threadIdx.x & 63;
    const int lrow = lane & 15;
    const int rowblk = mb * MROWS;
    const int k0   = kc * CHUNK;

    // x / hx share row stride 2048; a 1024-chunk never straddles them
    const float* Aglob = (kc < 2)
        ? (x  + (size_t)rowblk * IN_DIM + k0)
        : (hx + (size_t)rowblk * HIDDEN + (k0 - IN_DIM));
    const __bf16* Bglob = Wb + k0;

    // ---- staging addresses (pre-swizzled global source) ----
    // A: 4 instrs of 1 KB; instr p: row p*4 + (l>>4), dest unit l&15,
    //    src unit = (l&15) ^ (row&7).
    int aOff[4];
#pragma unroll
    for (int p = 0; p < 4; ++p) {
        const int r  = p * 4 + (lane >> 4);
        const int cs = (lane & 15) ^ (r & 7);
        aOff[p] = r * 2048 + cs * 4;            // float offset
    }
    // B: 4 instrs of 1 KB; instr i: row j = i*8 + (l>>3), dest unit l&7,
    //    src unit = (l&7) ^ (j&7).   (identical family to r10/r12, verified)
    int bOff[4];
#pragma unroll
    for (int i = 0; i < 4; ++i) {
        const int j = i * 8 + (lane >> 3);
        bOff[i] = j * KDIM + (((lane & 7) ^ (j & 7)) * 8);  // bf16 offset
    }

    // ---- swizzled ds_read_b128 byte offsets ----
    int offA0[2], offA1[2], offB0[2], offB1[2];
#pragma unroll
    for (int st = 0; st < 2; ++st) {
        const int cu = st * 8 + (lane >> 4) * 2;            // A 16B-unit
        offA0[st] = lrow * 256 + (((cu + 0) ^ (lane & 7)) * 16);
        offA1[st] = lrow * 256 + (((cu + 1) ^ (lane & 7)) * 16);
        const int cb = st * 4 + (lane >> 4);                // B 16B-unit
        offB0[st] = lrow * 128        + ((cb ^ (lrow & 7)) * 16);
        offB1[st] = (lrow + 16) * 128 + ((cb ^ (lrow & 7)) * 16);
    }

    f32x4 acc0 = {0.f, 0.f, 0.f, 0.f};   // j = lrow
    f32x4 acc1 = {0.f, 0.f, 0.f, 0.f};   // j = 16 + lrow

    auto issue = [&](int s) {
        const int b = s & (NBUF - 1);
#pragma unroll
        for (int p = 0; p < 4; ++p)
            gload_lds16(Aglob + aOff[p] + s * BK, &Abuf[b][p * 256]);
#pragma unroll
        for (int i = 0; i < 4; ++i)
            gload_lds16(Bglob + bOff[i] + s * BK, &Bbuf[b][i * 512]);
    };
    auto compute = [&](int s) {
        const int b = s & (NBUF - 1);
        const char* Ab = (const char*)&Abuf[b][0];
        const char* Bb = (const char*)&Bbuf[b][0];
#pragma unroll
        for (int st = 0; st < 2; ++st) {
            f32x4 a0 = *reinterpret_cast<const f32x4*>(Ab + offA0[st]);
            f32x4 a1 = *reinterpret_cast<const f32x4*>(Ab + offA1[st]);
            bf16x8 af = cvt8(a0, a1);
            bf16x8 b0 = *reinterpret_cast<const bf16x8*>(Bb + offB0[st]);
            bf16x8 b1 = *reinterpret_cast<const bf16x8*>(Bb + offB1[st]);
            acc0 = __builtin_amdgcn_mfma_f32_16x16x32_bf16(af, b0, acc0, 0, 0, 0);
            acc1 = __builtin_amdgcn_mfma_f32_16x16x32_bf16(af, b1, acc1, 0, 0, 0);
        }
    };

    // ---- BARRIER-FREE pipeline: depth-3 prefetch, counted per-wave vmcnt.
    // 8 loads/batch; outstanding after issue(s+3) = {s+1,s+2,s+3} = 24
    // -> vmcnt(24) implies batch s landed. Tail: 16, 8, 0.
    // Buffer safety (single wave, sequential): writer at iter s targets buf
    // (s+3)%4; the only concurrent reader is compute(s) on buf s%4 --
    // distance 3 mod 4 != 0. Prior contents of (s+3)%4 were consumed at
    // compute(s-1), which precedes issue(s+3) in program order.
    issue(0);
    issue(1);
    issue(2);
#pragma unroll
    for (int s = 0; s < SUBT; ++s) {
        if (s + 3 < SUBT) issue(s + 3);
        if (s < SUBT - 3)
            asm volatile("s_waitcnt vmcnt(24)" ::: "memory");
        else if (s == SUBT - 3)
            asm volatile("s_waitcnt vmcnt(16)" ::: "memory");
        else if (s == SUBT - 2)
            asm volatile("s_waitcnt vmcnt(8)" ::: "memory");
        else
            asm volatile("s_waitcnt vmcnt(0)" ::: "memory");
        __builtin_amdgcn_sched_barrier(0);      // no ds_read hoist (rule #18)
        compute(s);
    }

    // D layout (16x16x32): col = lane&15, row = (lane>>4)*4 + reg
    float* sp = Spart + ((size_t)kc * B_ROWS + rowblk) * NJ;
    const int m0 = (lane >> 4) * 4;
#pragma unroll
    for (int r = 0; r < 4; ++r) {
        sp[(size_t)(m0 + r) * NJ + lrow]      = acc0[r];
        sp[(size_t)(m0 + r) * NJ + 16 + lrow] = acc1[r];
    }
}

// ---------------- Pass 2: sum partials, bias, cos, reduce to q[4] ----------
// grid = 256 blocks * 256 thr = 65536 threads; each thread: 4 (row,j) pairs
extern "C" __global__ __launch_bounds__(256)
void p2_cos_reduce(const float* __restrict__ Spart,
                   const float* __restrict__ bf, const float* __restrict__ bi,
                   const float* __restrict__ bg, const float* __restrict__ bo,
                   float* __restrict__ q)
{
    __shared__ float ql[4];
    if (threadIdx.x < 4) ql[threadIdx.x] = 0.f;
    __syncthreads();

    const int t    = blockIdx.x * 256 + threadIdx.x;  // 0..65535
    const int j    = t & 31;
    const int gate = j >> 3;
    const float* Bp = (gate == 0) ? bf : (gate == 1) ? bi : (gate == 2) ? bg : bo;
    const float bj = Bp[j & 7];

    float accg = 0.f;
#pragma unroll
    for (int i = 0; i < 4; ++i) {
        const int row = (t >> 5) + i * 2048;
        float s = 0.f;
#pragma unroll
        for (int kc = 0; kc < KC; ++kc)
            s += Spart[((size_t)kc * B_ROWS + row) * NJ + j];
        accg += cosf(s + bj);
    }

    accg += __shfl_xor(accg, 1, 64);
    accg += __shfl_xor(accg, 2, 64);
    accg += __shfl_xor(accg, 4, 64);
    if ((threadIdx.x & 7) == 0) atomicAdd(&ql[gate], accg);
    __syncthreads();
    if (threadIdx.x < 4) atomicAdd(&q[threadIdx.x], ql[threadIdx.x]);
}

// ---------------- Pass 3: elementwise LSTM update ----------------
// cx: NORMAL load (re-read every replay -> keep L3-resident).
// out: NON-TEMPORAL store (write-once stream -> don't evict inputs from L3).
extern "C" __global__ __launch_bounds__(256)
void p3_elementwise(const float* __restrict__ cx, const float* __restrict__ q,
                    float* __restrict__ out)
{
    const float qf = q[0], qi = q[1], qg = q[2], qo = q[3];
    const float f  = 1.f / (1.f + expf(-qf));
    const float ii = 1.f / (1.f + expf(-qi));
    const float g  = tanhf(qg);
    const float o  = 1.f / (1.f + expf(-qo));
    const float ig = ii * g;

    const size_t N  = (size_t)B_ROWS * HIDDEN;
    const size_t N4 = N >> 2;
    const f32x4* cx4 = (const f32x4*)cx;
    f32x4* outh = (f32x4*)out;
    f32x4* outc = (f32x4*)(out + N);

    for (size_t idx = (size_t)blockIdx.x * blockDim.x + threadIdx.x; idx < N4;
         idx += (size_t)gridDim.x * blockDim.x) {
        f32x4 c = cx4[idx];                       // L3-resident across replays
        f32x4 cn, hn;
        cn.x = fmaf(f, c.x, ig);
        cn.y = fmaf(f, c.y, ig);
        cn.z = fmaf(f, c.z, ig);
        cn.w = fmaf(f, c.w, ig);
        hn.x = o * tanhf(cn.x);
        hn.y = o * tanhf(cn.y);
        hn.z = o * tanhf(cn.z);
        hn.w = o * tanhf(cn.w);
        __builtin_nontemporal_store(cn, outc + idx);
        __builtin_nontemporal_store(hn, outh + idx);
    }
}

// ---------------- launcher ----------------
extern "C" void kernel_launch(void* const* d_in, const int* in_sizes, int n_in,
                              void* d_out, int out_size, void* d_ws, size_t ws_size,
                              hipStream_t stream)
{
    const float* x  = (const float*)d_in[0];
    const float* hx = (const float*)d_in[1];
    const float* cx = (const float*)d_in[2];
    const float* Wf = (const float*)d_in[3];
    const float* bf = (const float*)d_in[4];
    const float* Wi = (const float*)d_in[5];
    const float* bi = (const float*)d_in[6];
    const float* Wg = (const float*)d_in[7];
    const float* bg = (const float*)d_in[8];
    const float* Wo = (const float*)d_in[9];
    const float* bo = (const float*)d_in[10];
    float* out = (float*)d_out;

    // ws layout: Spart [KC][8192][32] f32 (4 MB) | Wb [32][4096] bf16 | q[4]
    float*   Spart = (float*)d_ws;
    __bf16*  Wb    = (__bf16*)(Spart + (size_t)KC * B_ROWS * NJ);
    float*   q     = (float*)(Wb + (size_t)NJ * KDIM);

    w_pack<<<dim3(128), dim3(256), 0, stream>>>(Wf, Wi, Wg, Wo, Wb, q);
    p1_mfma<<<dim3(512 * KC), dim3(TPB1), 0, stream>>>(x, hx, Wb, Spart);
    p2_cos_reduce<<<dim3(256), dim3(256), 0, stream>>>(Spart, bf, bi, bg, bo, q);
    p3_elementwise<<<dim3(2048), dim3(256), 0, stream>>>(cx, q, out);
}

// Round 14
// 63.292 us; speedup vs baseline: 1.3950x; 1.1031x over previous
//
#include <hip/hip_runtime.h>
#include <hip/hip_bf16.h>
#include <cstdint>
#include <cstddef>

#define B_ROWS 8192
#define KDIM   4096
#define IN_DIM 2048
#define HIDDEN 2048
#define NJ     32           // 4 gates x 8 wires
#define KC     4            // K-split across blocks
#define CHUNK  (KDIM / KC)  // 1024
#define BK     64           // k-subtile per pipeline stage
#define SUBT   (CHUNK / BK) // 16
#define MROWS  16           // rows per block (ONE wave)
#define TPB1   64           // 1 wave -> no s_barrier anywhere in the K-loop
#define NBUF   3            // depth-2 prefetch (single-wave: distance-2 mod 3 safe)

typedef __bf16 bf16x8 __attribute__((ext_vector_type(8)));
typedef float  f32x4  __attribute__((ext_vector_type(4)));

__device__ __forceinline__ bf16x8 cvt8(f32x4 a, f32x4 b) {
    bf16x8 r;
    r[0] = (__bf16)a.x; r[1] = (__bf16)a.y; r[2] = (__bf16)a.z; r[3] = (__bf16)a.w;
    r[4] = (__bf16)b.x; r[5] = (__bf16)b.y; r[6] = (__bf16)b.z; r[7] = (__bf16)b.w;
    return r;
}

// async global->LDS, 16 B per lane; LDS dest = wave-uniform base + lane*16
__device__ __forceinline__ void gload_lds16(const void* g, void* lds) {
    __builtin_amdgcn_global_load_lds(
        (const __attribute__((address_space(1))) void*)g,
        (__attribute__((address_space(3))) void*)lds, 16, 0, 0);
}

// ---- Pass 1: split-K MFMA GEMM, barrier-free 1-wave pipelines, fp32 W ----
// grid = 512 mblocks * 4 kc = 2048 blocks of 64 thr (1 wave).
// LDS/buf: A fp32 [16][64] (4 KB) + W fp32 [32][64] (8 KB) = 12 KB; NBUF=3
// -> 36 KB/block -> 4 blocks/CU, independent depth-2 DMA pipelines.
// XOR swizzle both sides (rule #21): 16B-unit u ^= (row & 7).
// No w_pack: W staged fp32 straight from the four gate matrices (r11-verified
// slab addressing), converted to bf16 at consume. Spart: [KC][B_ROWS][NJ].
extern "C" __global__ __launch_bounds__(TPB1)
void p1_mfma(const float* __restrict__ x, const float* __restrict__ hx,
             const float* __restrict__ Wf, const float* __restrict__ Wi,
             const float* __restrict__ Wg, const float* __restrict__ Wo,
             float* __restrict__ Spart)
{
    __shared__ float Abuf[NBUF][MROWS * BK];   // 3 x 4 KB
    __shared__ float Bbuf[NBUF][NJ * BK];      // 3 x 8 KB

    const int bid  = blockIdx.x;
    const int kc   = bid & (KC - 1);
    const int mb   = bid >> 2;                  // 0..511
    const int lane = threadIdx.x & 63;
    const int lrow = lane & 15;
    const int rowblk = mb * MROWS;
    const int k0   = kc * CHUNK;

    // x / hx share row stride 2048; a 1024-chunk never straddles them
    const float* Aglob = (kc < 2)
        ? (x  + (size_t)rowblk * IN_DIM + k0)
        : (hx + (size_t)rowblk * HIDDEN + (k0 - IN_DIM));

    // ---- A staging (pre-swizzled source; r13-verified) ----
    // instr p: row r = p*4 + (l>>4), dest unit l&15, src unit = (l&15)^(r&7)
    int aOff[4];
#pragma unroll
    for (int p = 0; p < 4; ++p) {
        const int r  = p * 4 + (lane >> 4);
        const int cs = (lane & 15) ^ (r & 7);
        aOff[p] = r * 2048 + cs * 4;            // float offset
    }
    // ---- W staging (r11-verified slab addressing) ----
    // slab sl=0..7: rows j = sl*4 + (l>>4); gate = j>>3 -> {Wf,Wf,Wi,Wi,Wg,Wg,Wo,Wo}
    // src offset within gate matrix: (j&7)*KDIM + ((l&15)^(j&7))*4 floats
    const float* Wsrc[8] = {Wf, Wf, Wi, Wi, Wg, Wg, Wo, Wo};
    int bOffp[8];
#pragma unroll
    for (int sl = 0; sl < 8; ++sl) {
        const int j  = sl * 4 + (lane >> 4);
        const int j7 = j & 7;
        bOffp[sl] = j7 * KDIM + (((lane & 15) ^ j7) * 4);   // float offset
    }

    // ---- swizzled ds_read_b128 byte offsets (256 B row pitch, fp32) ----
    int offA0[2], offA1[2], offB00[2], offB01[2], offB10[2], offB11[2];
#pragma unroll
    for (int st = 0; st < 2; ++st) {
        const int cu = st * 8 + (lane >> 4) * 2;
        offA0[st]  = lrow * 256 + (((cu + 0) ^ (lane & 7)) * 16);
        offA1[st]  = lrow * 256 + (((cu + 1) ^ (lane & 7)) * 16);
        offB00[st] = lrow * 256        + (((cu + 0) ^ (lane & 7)) * 16);
        offB01[st] = lrow * 256        + (((cu + 1) ^ (lane & 7)) * 16);
        offB10[st] = (lrow + 16) * 256 + (((cu + 0) ^ (lane & 7)) * 16);
        offB11[st] = (lrow + 16) * 256 + (((cu + 1) ^ (lane & 7)) * 16);
    }

    f32x4 acc0 = {0.f, 0.f, 0.f, 0.f};   // j = lrow      (gates f,i)
    f32x4 acc1 = {0.f, 0.f, 0.f, 0.f};   // j = 16 + lrow (gates g,o)

    auto issue = [&](int s) {
        const int b = s % NBUF;
#pragma unroll
        for (int p = 0; p < 4; ++p)
            gload_lds16(Aglob + aOff[p] + s * BK, (char*)&Abuf[b][0] + p * 1024);
#pragma unroll
        for (int sl = 0; sl < 8; ++sl)
            gload_lds16(Wsrc[sl] + bOffp[sl] + k0 + s * BK,
                        (char*)&Bbuf[b][0] + sl * 1024);
    };
    auto compute = [&](int s) {
        const int b = s % NBUF;
        const char* Ab = (const char*)&Abuf[b][0];
        const char* Bb = (const char*)&Bbuf[b][0];
#pragma unroll
        for (int st = 0; st < 2; ++st) {
            f32x4 a0  = *reinterpret_cast<const f32x4*>(Ab + offA0[st]);
            f32x4 a1  = *reinterpret_cast<const f32x4*>(Ab + offA1[st]);
            f32x4 w00 = *reinterpret_cast<const f32x4*>(Bb + offB00[st]);
            f32x4 w01 = *reinterpret_cast<const f32x4*>(Bb + offB01[st]);
            f32x4 w10 = *reinterpret_cast<const f32x4*>(Bb + offB10[st]);
            f32x4 w11 = *reinterpret_cast<const f32x4*>(Bb + offB11[st]);
            bf16x8 af  = cvt8(a0, a1);
            bf16x8 bf0 = cvt8(w00, w01);
            bf16x8 bf1 = cvt8(w10, w11);
            acc0 = __builtin_amdgcn_mfma_f32_16x16x32_bf16(af, bf0, acc0, 0, 0, 0);
            acc1 = __builtin_amdgcn_mfma_f32_16x16x32_bf16(af, bf1, acc1, 0, 0, 0);
        }
    };

    // ---- BARRIER-FREE pipeline: depth-2 prefetch, counted per-wave vmcnt.
    // 12 loads/batch; outstanding after issue(s+2) = {s+1,s+2} = 24
    // -> vmcnt(24) implies batch s landed. Tail: 12, then 0.
    // Buffer safety (single wave, sequential): writer at iter s targets buf
    // (s+2)%3; the only concurrent reader is compute(s) on buf s%3 --
    // distance 2 mod 3 != 0; prior contents of (s+2)%3 were consumed at
    // compute(s-1), which precedes issue(s+2) in program order.
    issue(0);
    issue(1);
#pragma unroll
    for (int s = 0; s < SUBT; ++s) {
        if (s + 2 < SUBT) issue(s + 2);
        if (s < SUBT - 2)
            asm volatile("s_waitcnt vmcnt(24)" ::: "memory");
        else if (s == SUBT - 2)
            asm volatile("s_waitcnt vmcnt(12)" ::: "memory");
        else
            asm volatile("s_waitcnt vmcnt(0)" ::: "memory");
        __builtin_amdgcn_sched_barrier(0);      // no ds_read hoist (rule #18)
        compute(s);
    }

    // D layout (16x16x32): col = lane&15, row = (lane>>4)*4 + reg
    float* sp = Spart + ((size_t)kc * B_ROWS + rowblk) * NJ;
    const int m0 = (lane >> 4) * 4;
#pragma unroll
    for (int r = 0; r < 4; ++r) {
        sp[(size_t)(m0 + r) * NJ + lrow]      = acc0[r];
        sp[(size_t)(m0 + r) * NJ + 16 + lrow] = acc1[r];
    }
}

// ------ Pass 2: sum partials, bias, cos, per-block partial -> qpart -------
// grid = 256 blocks * 256 thr; each thread: 4 (row,j) pairs. No atomics.
extern "C" __global__ __launch_bounds__(256)
void p2_cos_reduce(const float* __restrict__ Spart,
                   const float* __restrict__ bf, const float* __restrict__ bi,
                   const float* __restrict__ bg, const float* __restrict__ bo,
                   float* __restrict__ qpart)
{
    __shared__ float ql[4];
    if (threadIdx.x < 4) ql[threadIdx.x] = 0.f;
    __syncthreads();

    const int t    = blockIdx.x * 256 + threadIdx.x;  // 0..65535
    const int j    = t & 31;
    const int gate = j >> 3;
    const float* Bp = (gate == 0) ? bf : (gate == 1) ? bi : (gate == 2) ? bg : bo;
    const float bj = Bp[j & 7];

    float accg = 0.f;
#pragma unroll
    for (int i = 0; i < 4; ++i) {
        const int row = (t >> 5) + i * 2048;
        float s = 0.f;
#pragma unroll
        for (int kc = 0; kc < KC; ++kc)
            s += Spart[((size_t)kc * B_ROWS + row) * NJ + j];
        accg += cosf(s + bj);
    }

    accg += __shfl_xor(accg, 1, 64);
    accg += __shfl_xor(accg, 2, 64);
    accg += __shfl_xor(accg, 4, 64);
    if ((threadIdx.x & 7) == 0) atomicAdd(&ql[gate], accg);   // LDS only
    __syncthreads();
    if (threadIdx.x < 4) qpart[blockIdx.x * 4 + threadIdx.x] = ql[threadIdx.x];
}

// -------- Pass 3: reduce qpart (4 KB, L2) + elementwise LSTM update -------
// cx: NORMAL load (re-read every replay -> keep L3-resident).
// out: NON-TEMPORAL store (write-once stream -> don't evict inputs from L3).
extern "C" __global__ __launch_bounds__(256)
void p3_elementwise(const float* __restrict__ cx, const float* __restrict__ qpart,
                    float* __restrict__ out)
{
    __shared__ float qs[4][4];                  // [wave][gate]
    const int tid  = threadIdx.x;
    const int wave = tid >> 6;
    const int lane = tid & 63;

    // block-local reduce of qpart[256][4] (one f32x4 per thread)
    f32x4 qp = *reinterpret_cast<const f32x4*>(qpart + tid * 4);
#pragma unroll
    for (int m = 1; m <= 32; m <<= 1) {
        qp.x += __shfl_xor(qp.x, m, 64);
        qp.y += __shfl_xor(qp.y, m, 64);
        qp.z += __shfl_xor(qp.z, m, 64);
        qp.w += __shfl_xor(qp.w, m, 64);
    }
    if (lane == 0) {
        qs[wave][0] = qp.x; qs[wave][1] = qp.y;
        qs[wave][2] = qp.z; qs[wave][3] = qp.w;
    }
    __syncthreads();
    const float qf = qs[0][0] + qs[1][0] + qs[2][0] + qs[3][0];
    const float qi = qs[0][1] + qs[1][1] + qs[2][1] + qs[3][1];
    const float qg = qs[0][2] + qs[1][2] + qs[2][2] + qs[3][2];
    const float qo = qs[0][3] + qs[1][3] + qs[2][3] + qs[3][3];

    const float f  = 1.f / (1.f + expf(-qf));
    const float ii = 1.f / (1.f + expf(-qi));
    const float g  = tanhf(qg);
    const float o  = 1.f / (1.f + expf(-qo));
    const float ig = ii * g;

    const size_t N  = (size_t)B_ROWS * HIDDEN;
    const size_t N4 = N >> 2;
    const f32x4* cx4 = (const f32x4*)cx;
    f32x4* outh = (f32x4*)out;
    f32x4* outc = (f32x4*)(out + N);

    for (size_t idx = (size_t)blockIdx.x * blockDim.x + tid; idx < N4;
         idx += (size_t)gridDim.x * blockDim.x) {
        f32x4 c = cx4[idx];                       // L3-resident across replays
        f32x4 cn, hn;
        cn.x = fmaf(f, c.x, ig);
        cn.y = fmaf(f, c.y, ig);
        cn.z = fmaf(f, c.z, ig);
        cn.w = fmaf(f, c.w, ig);
        hn.x = o * tanhf(cn.x);
        hn.y = o * tanhf(cn.y);
        hn.z = o * tanhf(cn.z);
        hn.w = o * tanhf(cn.w);
        __builtin_nontemporal_store(cn, outc + idx);
        __builtin_nontemporal_store(hn, outh + idx);
    }
}

// ---------------- launcher: THREE dispatches, no atomics, no memset -------
extern "C" void kernel_launch(void* const* d_in, const int* in_sizes, int n_in,
                              void* d_out, int out_size, void* d_ws, size_t ws_size,
                              hipStream_t stream)
{
    const float* x  = (const float*)d_in[0];
    const float* hx = (const float*)d_in[1];
    const float* cx = (const float*)d_in[2];
    const float* Wf = (const float*)d_in[3];
    const float* bf = (const float*)d_in[4];
    const float* Wi = (const float*)d_in[5];
    const float* bi = (const float*)d_in[6];
    const float* Wg = (const float*)d_in[7];
    const float* bg = (const float*)d_in[8];
    const float* Wo = (const float*)d_in[9];
    const float* bo = (const float*)d_in[10];
    float* out = (float*)d_out;

    // ws layout: Spart [KC][8192][32] f32 (4 MB) | qpart [256][4] f32
    float* Spart = (float*)d_ws;
    float* qpart = Spart + (size_t)KC * B_ROWS * NJ;

    p1_mfma<<<dim3(512 * KC), dim3(TPB1), 0, stream>>>(
        x, hx, Wf, Wi, Wg, Wo, Spart);
    p2_cos_reduce<<<dim3(256), dim3(256), 0, stream>>>(
        Spart, bf, bi, bg, bo, qpart);
    p3_elementwise<<<dim3(2048), dim3(256), 0, stream>>>(cx, qpart, out);
}